// Round 14
// baseline (434.088 us; speedup 1.0000x reference)
//
#include <hip/hip_runtime.h>

#define B_SZ 2048
#define T_SZ 2048

using f32x16 = float __attribute__((ext_vector_type(16)));

// DPP move: result[lane] = src[perm(lane)] (quad_perm / row_ror patterns)
template<int CTRL>
__device__ __forceinline__ float dppf(float v) {
  int r = __builtin_amdgcn_update_dpp(0, __builtin_bit_cast(int, v), CTRL, 0xf, 0xf, true);
  return __builtin_bit_cast(float, r);
}

#define SSTR 264                  // stage step stride in dwords (256 lanes + pad)
#define SBUF (8 * SSTR)           // one window buffer (8 steps)

// R13 staging skeleton + R10 scalar math (now that the store-WAR is gone):
// 4 rows/wave (16-lane group = row, lane owns units sl,sl+16,sl+32,sl+48),
// fully local state per lane, C-2R folded tanh tail, 4 PARALLEL 4-stage DPP
// butterflies (independent chains interleave -> hazard slots filled), zero
// broadcast, local y. Outputs staged per-step to LDS, flushed per 8-step
// window as coalesced wide global stores.
__global__ __launch_bounds__(256, 1) void sss_kernel(
    const float* __restrict__ x0p, const float* __restrict__ up,
    const float* __restrict__ tfp, const float* __restrict__ thp,
    const float* __restrict__ tup, const float* __restrict__ typ,
    const float* __restrict__ W1p, const float* __restrict__ b1p,
    const float* __restrict__ W2p, const float* __restrict__ Whp,
    float* __restrict__ outp)
{
  __shared__ float stageF[2 * SBUF];   // double-buffered by window parity

  const int tid  = threadIdx.x;
  const int lane = tid & 63;
  const int wv   = __builtin_amdgcn_readfirstlane((int)(tid >> 6));
  const int grp  = lane >> 4;              // 16-lane group = row within wave
  const int sl   = lane & 15;              // sub-lane within group
  const int b0   = blockIdx.x * 16 + wv * 4;
  const int b    = b0 + grp;               // this lane's batch row

  // ---- prologue ----
  // fold K = 2*log2(e) into W1/cc: tanh(a) = 1 - 2*rcp(exp2(K*a)+1)
  const float K = 2.8853900817779268f;
  float w1_[4][6], cc[4];
#pragma unroll
  for (int i = 0; i < 4; ++i) {
    const int u = sl + 16 * i;
#pragma unroll
    for (int r = 0; r < 6; ++r) w1_[i][r] = W1p[r * 64 + u] * K;
    float t = b1p[u];
#pragma unroll
    for (int q = 0; q < 5; ++q) t = fmaf(tfp[q], W1p[(6 + q) * 64 + u], t);
    cc[i] = t * K;
  }

  const float scale = tup[0] / typ[0];
  // w2t[k][i] = scale * W2[sl+16i][k]
  float w2t[4][4];
#pragma unroll
  for (int i = 0; i < 4; ++i) {
    const float4 w2r = ((const float4*)W2p)[sl + 16 * i];
    w2t[0][i] = w2r.x * scale;
    w2t[1][i] = w2r.y * scale;
    w2t[2][i] = w2r.z * scale;
    w2t[3][i] = w2r.w * scale;
  }

  // C_k = sum over all 64 units of w2t (loop-invariant): partial + butterfly
  float C0 = (w2t[0][0] + w2t[0][1]) + (w2t[0][2] + w2t[0][3]);
  float C1 = (w2t[1][0] + w2t[1][1]) + (w2t[1][2] + w2t[1][3]);
  float C2 = (w2t[2][0] + w2t[2][1]) + (w2t[2][2] + w2t[2][3]);
  float C3 = (w2t[3][0] + w2t[3][1]) + (w2t[3][2] + w2t[3][3]);
  C0 += dppf<0xB1>(C0);  C1 += dppf<0xB1>(C1);  C2 += dppf<0xB1>(C2);  C3 += dppf<0xB1>(C3);
  C0 += dppf<0x4E>(C0);  C1 += dppf<0x4E>(C1);  C2 += dppf<0x4E>(C2);  C3 += dppf<0x4E>(C3);
  C0 += dppf<0x124>(C0); C1 += dppf<0x124>(C1); C2 += dppf<0x124>(C2); C3 += dppf<0x124>(C3);
  C0 += dppf<0x128>(C0); C1 += dppf<0x128>(C1); C2 += dppf<0x128>(C2); C3 += dppf<0x128>(C3);

  const float wh0 = Whp[0], wh1 = Whp[1], wh2 = Whp[2], wh3 = Whp[3];
  const float th  = thp[0];

  // per-lane local state (all 4 components)
  float x0 = x0p[b * 4 + 0];
  float x1 = x0p[b * 4 + 1];
  float x2 = x0p[b * 4 + 2];
  float x3 = x0p[b * 4 + 3];
  float xC0 = x0 + C0, xC1 = x1 + C1, xC2 = x2 + C2, xC3 = x3 + C3;

  // y0 = h(x_0), UNCLAMPED (matches reference)
  float yv = fmaf(x0, wh0, fmaf(x1, wh1, fmaf(x2, wh2, fmaf(x3, wh3, th))));

  // staging select bits
  const bool s1  = sl & 1;
  const bool s2  = sl & 2;
  const bool is4 = (sl == 4);

  // ---- staging / flush address setup (all loop-invariant, R13-proven) ----
  const int m   = sl;
  const int xr  = lane >> 4;
  const int t0  = m >> 1;
  const int k0  = (2 * m) & 3;
  const int rdoff = t0 * SSTR + wv * 64 + 16 * xr + k0;       // dwords
  const int yoff  = (lane & 7) * SSTR + wv * 64 + 16 * (lane >> 3) + 4;
  float2* gxp = (float2*)outp + (size_t)(b0 + (lane >> 4)) * (T_SZ * 2) + (lane & 15);
  float*  gyp = outp + (size_t)B_SZ * T_SZ * 4 + (size_t)(b0 + (lane >> 3)) * T_SZ + (lane & 7);

  const f32x16* up16 = (const f32x16*)(up + (size_t)b * (T_SZ * 2)); // 8 steps/chunk
  f32x16 uch = up16[0];
  const int NC = T_SZ / 8;

  for (int c = 0; c < NC; ++c) {
    const int g = (c + 1 < NC) ? c + 1 : NC - 1;   // prefetch next chunk
    const f32x16 unx = up16[g];
    float* sw = &stageF[(c & 1) * SBUF + tid];     // this window's write base
#pragma unroll
    for (int jj = 0; jj < 8; ++jj) {
      // ---- capture PRE-update carry (x_step, y_step) into LDS ----
      const float vlow  = s1 ? x1 : x0;
      const float vhigh = s1 ? x3 : x2;
      const float vx    = s2 ? vhigh : vlow;
      const float vdata = is4 ? yv : vx;
      sw[jj * SSTR] = vdata;                       // ds_write_b32, fire-forget

      const float u0 = uch[2 * jj];
      const float u1 = uch[2 * jj + 1];

      // pre-activation + r = rcp(exp2(acc)+1), 4 units (scalar, no splats)
      float r_[4];
#pragma unroll
      for (int i = 0; i < 4; ++i) {
        const float base = fmaf(u1, w1_[i][5], fmaf(u0, w1_[i][4], cc[i]));
        const float m23  = fmaf(x2, w1_[i][2], x3 * w1_[i][3]);
        const float m01  = fmaf(x1, w1_[i][1], x0 * w1_[i][0]);
        const float acc  = (base + m23) + m01;
        const float e    = __builtin_amdgcn_exp2f(acc);
        r_[i] = __builtin_amdgcn_rcpf(e + 1.0f);
      }

      // R_k = sum r_i * w2t[k][i] (depth-3 trees, 4 parallel channels)
      float R0 = fmaf(r_[1], w2t[0][1], r_[0] * w2t[0][0]) + fmaf(r_[3], w2t[0][3], r_[2] * w2t[0][2]);
      float R1 = fmaf(r_[1], w2t[1][1], r_[0] * w2t[1][0]) + fmaf(r_[3], w2t[1][3], r_[2] * w2t[1][2]);
      float R2 = fmaf(r_[1], w2t[2][1], r_[0] * w2t[2][0]) + fmaf(r_[3], w2t[2][3], r_[2] * w2t[2][2]);
      float R3 = fmaf(r_[1], w2t[3][1], r_[0] * w2t[3][0]) + fmaf(r_[3], w2t[3][3], r_[2] * w2t[3][2]);

      // 16-lane all-reduce: 4 INDEPENDENT butterflies interleaved
      R0 += dppf<0xB1>(R0);  R1 += dppf<0xB1>(R1);  R2 += dppf<0xB1>(R2);  R3 += dppf<0xB1>(R3);
      R0 += dppf<0x4E>(R0);  R1 += dppf<0x4E>(R1);  R2 += dppf<0x4E>(R2);  R3 += dppf<0x4E>(R3);
      R0 += dppf<0x124>(R0); R1 += dppf<0x124>(R1); R2 += dppf<0x124>(R2); R3 += dppf<0x124>(R3);
      R0 += dppf<0x128>(R0); R1 += dppf<0x128>(R1); R2 += dppf<0x128>(R2); R3 += dppf<0x128>(R3);

      // w_k = x_k + (C_k - 2 R_k) = fma(-2, R_k, xC_k): pre-clip x_raw
      const float wr0 = fmaf(-2.0f, R0, xC0);
      const float wr1 = fmaf(-2.0f, R1, xC1);
      const float wr2 = fmaf(-2.0f, R2, xC2);
      const float wr3 = fmaf(-2.0f, R3, xC3);

      // y from PRE-clip state (local, off-chain)
      const float yy = fmaf(wr0, wh0, fmaf(wr1, wh1, fmaf(wr2, wh2, wr3 * wh3)));
      yv = __builtin_amdgcn_fmed3f(yy + th, 0.0f, 10.0f);

      // clip: channels 0..2 -> [0,10], channel 3 unbounded
      x0 = __builtin_amdgcn_fmed3f(wr0, 0.0f, 10.0f);
      x1 = __builtin_amdgcn_fmed3f(wr1, 0.0f, 10.0f);
      x2 = __builtin_amdgcn_fmed3f(wr2, 0.0f, 10.0f);
      x3 = wr3;
      xC0 = x0 + C0; xC1 = x1 + C1; xC2 = x2 + C2; xC3 = x3 + C3;  // off-chain
    }
    // ---- window flush: LDS transpose -> coalesced wide stores (R13-proven) ----
    {
      const int bb = (c & 1) * SBUF;
      const float2 xv = *(const float2*)&stageF[bb + rdoff];  // ds_read_b64
      *gxp = xv;                                              // dwordx2, coalesced
      if (lane < 32) {
        const float yy2 = stageF[bb + yoff];
        *gyp = yy2;
      }
      gxp += 16;   // 32 floats (8 steps x 4 ch) per row per window
      gyp += 8;
    }
    uch = unx;
  }
}

extern "C" void kernel_launch(void* const* d_in, const int* in_sizes, int n_in,
                              void* d_out, int out_size, void* d_ws, size_t ws_size,
                              hipStream_t stream) {
  (void)in_sizes; (void)n_in; (void)out_size; (void)d_ws; (void)ws_size;
  sss_kernel<<<dim3(B_SZ / 16), dim3(256), 0, stream>>>(
      (const float*)d_in[0], (const float*)d_in[1], (const float*)d_in[2],
      (const float*)d_in[3], (const float*)d_in[4], (const float*)d_in[5],
      (const float*)d_in[6], (const float*)d_in[7], (const float*)d_in[8],
      (const float*)d_in[9], (float*)d_out);
}